// Round 10
// baseline (189.828 us; speedup 1.0000x reference)
//
#include <hip/hip_runtime.h>
#include <stdint.h>

// SplitAttention: x->(x_tok|x_pos); Q=x_pos@Wq K=x_pos@Wk V=x_tok@Wv;
// causal 16-head attention (d=64); out = attn @ Wo. All MFMA bf16.
//
// R16: attn cross-iteration pipelining -- PV(it-1) executes inside iter it,
// adjacent to QK(it), so two independent MFMA streams fill the matrix pipe
// while softmax(it) runs on VALU (MfmaUtil was 35% with the pipe idle
// during the serial QK->exp2->pack->PV chain). ONE barrier/iter kept:
// V LDS triple-buffered (PV(it-1) reads Vs[(it-1)%3]; writes(it+1) target
// Vs[(it+1)%3]; barrier-ordering covers reuse distances 2 (K) and 3 (V)).
// LDS 40KB, P-frags live one iter (+16 VGPR ~ 90, (256,3) cap 170).
// GEMMs/prep frozen (R15) for attribution.

typedef unsigned short u16;
typedef __bf16 bf16;
typedef bf16 bf16x8 __attribute__((ext_vector_type(8)));
typedef u16 u16x8 __attribute__((ext_vector_type(8)));
typedef u16 u16x4 __attribute__((ext_vector_type(4)));
typedef float f32x4 __attribute__((ext_vector_type(4)));
typedef uint32_t u32x4 __attribute__((ext_vector_type(4)));

__device__ __forceinline__ u16 cvt_bf16(float f) {
  uint32_t u = __builtin_bit_cast(uint32_t, f);
  u += 0x7FFFu + ((u >> 16) & 1u);   // RNE
  return (u16)(u >> 16);
}

__device__ __forceinline__ f32x4 mfma_bf(bf16x8 a, bf16x8 b, f32x4 c) {
  return __builtin_amdgcn_mfma_f32_16x16x32_bf16(a, b, c, 0, 0, 0);
}

typedef __attribute__((address_space(1))) const uint32_t g_u32;
typedef __attribute__((address_space(3))) uint32_t l_u32;
__device__ __forceinline__ void gload16(const u16* g, u16* l) {
  __builtin_amdgcn_global_load_lds((g_u32*)g, (l_u32*)l, 16, 0, 0);
}

// ---------------- merged prep: gid<1024 -> W[k][n] f32 -> Wt[n][k] bf16
// (z=0..2: 512x1024; z=3: Wo 1024x1024); gid>=1024 -> x -> tok/pos split.
__global__ __launch_bounds__(256) void prep(
    const float* __restrict__ x, const float* __restrict__ Wq,
    const float* __restrict__ Wk, const float* __restrict__ Wv,
    const float* __restrict__ Wo, u16* __restrict__ xtok,
    u16* __restrict__ xpos, u16* __restrict__ Wt, u16* __restrict__ WoT) {
  const int gid = blockIdx.x;
  const int tid = threadIdx.x;
  if (gid < 1024) {
    const int z = gid >> 8;
    const float* src = (z == 0) ? Wq : (z == 1) ? Wk : (z == 2) ? Wv : Wo;
    const int K = (z == 3) ? 1024 : 512;
    u16* dst = (z == 3) ? WoT : (Wt + (size_t)z * 1024 * 512);
    const int k0 = ((gid >> 4) & 15) * 64, n0 = (gid & 15) * 64;
    if (k0 >= K) return;
    __shared__ u16 T[64][68];
    const int r = tid >> 4, c = (tid & 15) * 4;
#pragma unroll
    for (int i = 0; i < 4; i++) {
      float4 v = *(const float4*)(src + (size_t)(k0 + r + i * 16) * 1024 + n0 + c);
      u16x4 b = {cvt_bf16(v.x), cvt_bf16(v.y), cvt_bf16(v.z), cvt_bf16(v.w)};
      *(u16x4*)&T[r + i * 16][c] = b;
    }
    __syncthreads();
#pragma unroll
    for (int i = 0; i < 4; i++) {
      int n = r + i * 16;
      u16x4 v;
#pragma unroll
      for (int j = 0; j < 4; j++) v[j] = T[c + j][n];
      *(u16x4*)(dst + (size_t)(n0 + n) * K + k0 + c) = v;
    }
  } else {
    int idx = (gid - 1024) * 256 + tid;
    int row = idx >> 8;
    int c4 = (idx & 255) * 4;
    float4 v = *(const float4*)(x + (size_t)row * 1024 + c4);
    u16x4 b = {cvt_bf16(v.x), cvt_bf16(v.y), cvt_bf16(v.z), cvt_bf16(v.w)};
    u16* dst = (c4 < 512) ? (xtok + (size_t)row * 512 + c4)
                          : (xpos + (size_t)row * 512 + c4 - 512);
    *(u16x4*)dst = b;
  }
}

// ================= 128x128 BK=32 triple-buffer GEMM core =================
// 256 threads = 4 waves (2M x 2N), per-wave C = 64x64, acc[4][4].
// LDS 48KB -> 3 blocks/CU. One phase per K-tile t: {8 ds_read_b128/wave of
// buf t%3 || stage tile t+2 -> buf (t+2)%3 (4 gload_lds/thread) -> barrier
// -> lgkmcnt(0) -> 16 MFMA -> vmcnt(4) -> barrier}. WAR-safe: staged buf
// != read buf; its last readers drained one barrier earlier.
// Rows are 4x 16B slots; XOR swizzle slot^=(row&3) both-sides.

#define YLD(P) {                                                             \
  const u16* pa_ = rA + (P)*4096;                                            \
  af[0] = *(const bf16x8*)(pa_ + 0*512 + colx);                              \
  af[1] = *(const bf16x8*)(pa_ + 1*512 + colx);                              \
  af[2] = *(const bf16x8*)(pa_ + 2*512 + colx);                              \
  af[3] = *(const bf16x8*)(pa_ + 3*512 + colx);                              \
  const u16* pb_ = rB + (P)*4096;                                            \
  bf[0] = *(const bf16x8*)(pb_ + 0*512 + colx);                              \
  bf[1] = *(const bf16x8*)(pb_ + 1*512 + colx);                              \
  bf[2] = *(const bf16x8*)(pb_ + 2*512 + colx);                              \
  bf[3] = *(const bf16x8*)(pb_ + 3*512 + colx); }

#define YMM {                                                                \
  acc[0][0] = mfma_bf(af[0], bf[0], acc[0][0]);                              \
  acc[0][1] = mfma_bf(af[0], bf[1], acc[0][1]);                              \
  acc[0][2] = mfma_bf(af[0], bf[2], acc[0][2]);                              \
  acc[0][3] = mfma_bf(af[0], bf[3], acc[0][3]);                              \
  acc[1][0] = mfma_bf(af[1], bf[0], acc[1][0]);                              \
  acc[1][1] = mfma_bf(af[1], bf[1], acc[1][1]);                              \
  acc[1][2] = mfma_bf(af[1], bf[2], acc[1][2]);                              \
  acc[1][3] = mfma_bf(af[1], bf[3], acc[1][3]);                              \
  acc[2][0] = mfma_bf(af[2], bf[0], acc[2][0]);                              \
  acc[2][1] = mfma_bf(af[2], bf[1], acc[2][1]);                              \
  acc[2][2] = mfma_bf(af[2], bf[2], acc[2][2]);                              \
  acc[2][3] = mfma_bf(af[2], bf[3], acc[2][3]);                              \
  acc[3][0] = mfma_bf(af[3], bf[0], acc[3][0]);                              \
  acc[3][1] = mfma_bf(af[3], bf[1], acc[3][1]);                              \
  acc[3][2] = mfma_bf(af[3], bf[2], acc[3][2]);                              \
  acc[3][3] = mfma_bf(af[3], bf[3], acc[3][3]); }

#define YST(P, KT) {                                                         \
  gload16(gA + (KT)*32, lA + (P)*4096);                                      \
  gload16(gA + (size_t)64*Kd + (KT)*32, lA + (P)*4096 + 2048);               \
  gload16(gB + (KT)*32, lB + (P)*4096);                                      \
  gload16(gB + (size_t)64*Kd + (KT)*32, lB + (P)*4096 + 2048); }

#define YPH_MID  asm volatile("" ::: "memory"); __builtin_amdgcn_s_barrier();\
  asm volatile("s_waitcnt lgkmcnt(0)" ::: "memory");                         \
  __builtin_amdgcn_s_setprio(1);

#define YPH_END  __builtin_amdgcn_s_setprio(0);                              \
  asm volatile("s_waitcnt vmcnt(4)" ::: "memory");                           \
  asm volatile("" ::: "memory"); __builtin_amdgcn_s_barrier();

template <int Kd>
__device__ __forceinline__ void gemm128_core(
    const u16* __restrict__ Aptr, const u16* __restrict__ Bptr,
    int m0, int n0, u16* smem, f32x4 (&acc)[4][4]) {
  constexpr int NKT = Kd / 32;
  const int tid = threadIdx.x;
  const int lane = tid & 63;
  const int mrow = lane & 15, quad = lane >> 4;
  const int w = tid >> 6, wm = w >> 1, wn = w & 1;

  u16* As = smem;                 // 3 x 4096 u16 (8KB per buf)
  u16* Bs = smem + 12288;         // 3 x 4096 u16

  // staging: thread -> (row = tid>>2 (+64 second load), 16B slot = tid&3)
  const int lrs = tid >> 2, sp4 = tid & 3;
  const int slog = sp4 ^ (lrs & 3);          // pre-swizzled global slot
  const u16* gA = Aptr + (size_t)(m0 + lrs) * Kd + slog * 8;
  const u16* gB = Bptr + (size_t)(n0 + lrs) * Kd + slog * 8;
  u16* lA = As + tid * 8;
  u16* lB = Bs + tid * 8;

  // reads: swizzled slot offset (u16 units), key = (mrow&3)*8
  const int colx = ((quad ^ (mrow & 3)) * 8);
  const u16* rA = As + (wm * 64 + mrow) * 32;
  const u16* rB = Bs + (wn * 64 + mrow) * 32;

  bf16x8 af[4], bf[4];

  // prologue: stage tiles 0 (buf0) and 1 (buf1); gate tile 0 -> vmcnt(4)
  YST(0, 0) YST(1, 1)
  asm volatile("s_waitcnt vmcnt(4)" ::: "memory");
  asm volatile("" ::: "memory");
  __builtin_amdgcn_s_barrier();

  int p = 0, ps = 2;
  for (int t = 0; t < NKT; ++t) {
    const int kt = (t + 2 < NKT) ? t + 2 : NKT - 1;  // clamp keeps vmcnt uniform
    YLD(p)
    YST(ps, kt)
    YPH_MID
    YMM
    YPH_END
    p = (p == 2) ? 0 : p + 1;
    ps = (ps == 2) ? 0 : ps + 1;
  }
  asm volatile("s_waitcnt vmcnt(0)" ::: "memory");  // drain clamped tail stages
  __builtin_amdgcn_s_barrier();
}

// XCD-aware remap (bijective, nwg = 8*64 = 512, 512%8 == 0): each XCD gets
// 64 consecutive work-ids = an 8x8 tile patch (A panel 1MB + B 1MB ~ L2).
__device__ __forceinline__ void xcd_remap(int& bx, int& by) {
  int flat = blockIdx.x + 8 * blockIdx.y;
  int wg = (flat & 7) * 64 + (flat >> 3);
  bx = wg & 7;
  by = wg >> 3;
}

// ---------------- QKV projection, 128x128 BK=32 triple-buffer
__global__ __launch_bounds__(256, 3) void gemm_qkv128(
    const u16* __restrict__ xtok, const u16* __restrict__ xpos,
    const u16* __restrict__ Wt, u16* __restrict__ qkv,
    u16* __restrict__ vperm) {
  const int z = blockIdx.z;
  const u16* A = (z == 2) ? xtok : xpos;
  const u16* Bt = Wt + (size_t)z * 1024 * 512;
  u16* outp = qkv + (size_t)z * (64u * 2048u * 64u);
  const float osc = (z == 0) ? 0.18033688011112042f : 1.0f;  // 0.125*log2e
  int bx, by;
  xcd_remap(bx, by);
  const int m0 = by * 128, n0 = bx * 128;

  __shared__ __align__(16) u16 smem[24576];
  f32x4 acc[4][4];
#pragma unroll
  for (int i = 0; i < 4; i++)
#pragma unroll
    for (int j = 0; j < 4; j++) acc[i][j] = (f32x4){0.f, 0.f, 0.f, 0.f};

  gemm128_core<512>(A, Bt, m0, n0, smem, acc);

  const int tid = threadIdx.x;
  const int lane = tid & 63;
  const int mrow = lane & 15, quad = lane >> 4;
  const int w = tid >> 6, wm = w >> 1, wn = w & 1;

  if (z != 2) {
#pragma unroll
    for (int mi = 0; mi < 4; mi++)
#pragma unroll
      for (int ni = 0; ni < 4; ni++)
#pragma unroll
        for (int r = 0; r < 4; r++) {
          int m = m0 + wm * 64 + mi * 16 + quad * 4 + r;
          int n = n0 + wn * 64 + ni * 16 + mrow;
          int bb = m >> 11, t = m & 2047;
          int h = n >> 6, d = n & 63;
          outp[(((size_t)(bb * 16 + h)) * 2048 + t) * 64 + d] =
              cvt_bf16(acc[mi][ni][r] * osc);
        }
  } else {
#pragma unroll
    for (int mi = 0; mi < 4; mi++)
#pragma unroll
      for (int ni = 0; ni < 4; ni++)
#pragma unroll
        for (int r = 0; r < 4; r++) {
          int m = m0 + wm * 64 + mi * 16 + quad * 4 + r;
          int n = n0 + wn * 64 + ni * 16 + mrow;
          int bb = m >> 11, t = m & 2047;
          int h = n >> 6, d = n & 63;
          int k6 = t & 63;
          int pos = (k6 & 32) + ((k6 >> 4) & 1) * 4 + ((k6 >> 2) & 3) * 8 +
                    (k6 & 3);
          vperm[(((size_t)(bb * 16 + h)) * 64 + d) * 2048 + (t & ~63) + pos] =
              cvt_bf16(acc[mi][ni][r]);
        }
  }
}

// ---------------- Output projection, 128x128 BK=32 triple-buffer -> f32
__global__ __launch_bounds__(256, 3) void gemm_out128(
    const u16* __restrict__ Am, const u16* __restrict__ WoT,
    float* __restrict__ out) {
  int bx, by;
  xcd_remap(bx, by);
  const int m0 = by * 128, n0 = bx * 128;

  __shared__ __align__(16) u16 smem[24576];
  f32x4 acc[4][4];
#pragma unroll
  for (int i = 0; i < 4; i++)
#pragma unroll
    for (int j = 0; j < 4; j++) acc[i][j] = (f32x4){0.f, 0.f, 0.f, 0.f};

  gemm128_core<1024>(Am, WoT, m0, n0, smem, acc);

  const int tid = threadIdx.x;
  const int lane = tid & 63;
  const int mrow = lane & 15, quad = lane >> 4;
  const int w = tid >> 6, wm = w >> 1, wn = w & 1;

#pragma unroll
  for (int mi = 0; mi < 4; mi++)
#pragma unroll
    for (int ni = 0; ni < 4; ni++)
#pragma unroll
      for (int r = 0; r < 4; r++) {
        int m = m0 + wm * 64 + mi * 16 + quad * 4 + r;
        int n = n0 + wn * 64 + ni * 16 + mrow;
        out[(size_t)m * 1024 + n] = acc[mi][ni][r];
      }
}

// ---------------- Flash attention (S^T / O^T, no max, 128-row q-tiles)
// Cross-iteration pipelined: iter it = {stage K/V(it) -> LDS; prefetch
// it+1; ONE barrier; QK(it); PV(it-1) [adjacent MFMA streams]; softmax(it)
// -> P frags kept in registers for next iter}. K double-buffered (reuse
// distance 2), V TRIPLE-buffered (PV(it-1) reads Vs[(it-1)%3] while
// writes(it+1) hit Vs[(it+1)%3]; all reads of a buffer complete >=1
// barrier before its rewrite -- same invariant as R10, distances 2 and 3).
// Causal skip is monotone so the pending-PV flush after the loop is exact.
// LDS 40KB (4 blocks/CU); epilogue Osh overlays.
__global__ __launch_bounds__(256, 3) void attn(
    const u16* __restrict__ qkv, const u16* __restrict__ vperm,
    u16* __restrict__ aout) {
  const int bh = blockIdx.x;
  const int qt = 15 - blockIdx.y;   // 128-row q-tile, longest first
  const int bb = bh >> 4, h = bh & 15;
  const u16* Qp = qkv + (size_t)bh * (2048 * 64);
  const u16* Kp = qkv + (size_t)(64 + bh) * (2048 * 64);
  const u16* Vp = vperm + (size_t)bh * (64 * 2048);

  // 40KB flat: Ks[2 buf][2 sec][2048] | Vs[3 buf][2 sec][2048]; Osh overlays
  __shared__ __align__(16) u16 smem[20480];
  u16* Ks = smem;            // + (it&1)*4096
  u16* Vs = smem + 8192;     // + (it%3)*4096

  const int tid = threadIdx.x;
  const int lane = tid & 63;
  const int w = tid >> 6;
  const int mrow = lane & 15;
  const int quad = lane >> 4;
  const int srow = w * 16 + (lane >> 2);
  const int sc = (lane & 3) * 8;
  const int soff = srow * 32 + sc;

  const u16x8 onesu = {0x3F80, 0x3F80, 0x3F80, 0x3F80,
                       0x3F80, 0x3F80, 0x3F80, 0x3F80};
  const bf16x8 ones = __builtin_bit_cast(bf16x8, onesu);

  const u16* kgb = Kp + (size_t)srow * 64 + sc;   // + k0*64 per tile
  const u16* vgb = Vp + (size_t)srow * 2048 + sc; // + k0 per tile

  const int q0 = qt * 128;
  const int nk = 2 * qt + 2;
  const int qw = q0 + w * 32;                  // wave's first q row

  const u16* qbase = Qp + (size_t)(qw + mrow) * 64 + quad * 8;
  const bf16x8 qf00 = *(const bf16x8*)qbase;             // g=0, d 0..31
  const bf16x8 qf01 = *(const bf16x8*)(qbase + 32);      // g=0, d 32..63
  const bf16x8 qf10 = *(const bf16x8*)(qbase + 16 * 64);       // g=1
  const bf16x8 qf11 = *(const bf16x8*)(qbase + 16 * 64 + 32);  // g=1

  f32x4 o[2][4], ol[2];
  bf16x8 pfp[2][2];   // P frags of the previously computed tile
#pragma unroll
  for (int g = 0; g < 2; ++g) {
#pragma unroll
    for (int dt = 0; dt < 4; ++dt) o[g][dt] = (f32x4){0.f, 0.f, 0.f, 0.f};
    ol[g] = (f32x4){0.f, 0.f, 0.f, 0.f};
    pfp[g][0] = __builtin_bit_cast(bf16x8, (u16x8){0,0,0,0,0,0,0,0});
    pfp[g][1] = pfp[g][0];
  }

  // prefetch tile 0
  u16x8 ka0 = *(const u16x8*)kgb;
  u16x8 ka1 = *(const u16x8*)(kgb + 32);
  u16x8 va0 = *(const u16x8*)vgb;
  u16x8 va1 = *(const u16x8*)(vgb + 32);

  int vb = 0;                 // V write slot (it % 3)
  const u16* vbPrev = Vs;     // V buffer of tile it-1

  for (int it = 0; it < nk; ++it) {
    u16* kw = Ks + (it & 1) * 4096;
    u16* vw = Vs + vb * 4096;
    *(u16x8*)(kw + soff) = ka0;
    *(u16x8*)(kw + 2048 + soff) = ka1;
    *(u16x8*)(vw + soff) = va0;
    *(u16x8*)(vw + 2048 + soff) = va1;

    if (it + 1 < nk) {   // issue next tile's loads; land during compute
      const int kn = (it + 1) * 64;
      ka0 = *(const u16x8*)(kgb + (size_t)kn * 64);
      ka1 = *(const u16x8*)(kgb + (size_t)kn * 64 + 32);
      va0 = *(const u16x8*)(vgb + kn);
      va1 = *(const u16x8*)(vgb + kn + 32);
    }

    __syncthreads();   // tile it visible; rewritten buffers' readers done

    const int k0 = it * 64;
    const bool doQK = (k0 <= qw + 31);

    // S^T = K · Q^T  (C: row = key-in-tile = quad*4+r, col = q = mrow)
    f32x4 s[2][4];
    if (doQK) {
#pragma unroll
      for (int nt = 0; nt < 4; ++nt) {
        bf16x8 kf0 = *(const bf16x8*)(kw + (nt * 16 + mrow) * 32 + quad * 8);
        bf16x8 kf1 =
            *(const bf16x8*)(kw + 2048 + (nt * 16 + mrow) * 32 + quad * 8);
        f32x4 z0 = (f32x4){0.f, 0.f, 0.f, 0.f};
        z0 = mfma_bf(kf0, qf00, z0);
        s[0][nt] = mfma_bf(kf1, qf01, z0);
        f32x4 z1 = (f32x4){0.f, 0.f, 0.f, 0.f};
        z1 = mfma_bf(kf0, qf10, z1);
        s[1][nt] = mfma_bf(kf1, qf11, z1);
      }
    }

    // PV(it-1): independent MFMA stream, fills the pipe during softmax(it)
    if (it > 0 && k0 - 64 <= qw + 31) {
#pragma unroll
      for (int dt = 0; dt < 4; ++dt) {
        bf16x8 vf0 =
            *(const bf16x8*)(vbPrev + (dt * 16 + mrow) * 32 + quad * 8);
        bf16x8 vf1 =
            *(const bf16x8*)(vbPrev + 2048 + (dt * 16 + mrow) * 32 + quad * 8);
        o[0][dt] = mfma_bf(vf0, pfp[0][0], o[0][dt]);
        o[0][dt] = mfma_bf(vf1, pfp[0][1], o[0][dt]);
        o[1][dt] = mfma_bf(vf0, pfp[1][0], o[1][dt]);
        o[1][dt] = mfma_bf(vf1, pfp[1][1], o[1][dt]);
      }
    }

    if (doQK) {
      if (k0 + 63 > qw) {   // diagonal tile for this wave: causal mask
#pragma unroll
        for (int g = 0; g < 2; ++g)
#pragma unroll
          for (int nt = 0; nt < 4; ++nt)
#pragma unroll
            for (int r = 0; r < 4; ++r)
              if (k0 + nt * 16 + quad * 4 + r > qw + g * 16 + mrow)
                s[g][nt][r] = -1e30f;
      }
      // p = exp2(s), no max subtraction (|s| bounded << 127)
#pragma unroll
      for (int g = 0; g < 2; ++g)
#pragma unroll
        for (int nt = 0; nt < 4; ++nt)
#pragma unroll
          for (int r = 0; r < 4; ++r)
            s[g][nt][r] = __builtin_amdgcn_exp2f(s[g][nt][r]);

      // P^T B-frags: compiler pairs casts into v_cvt_pk_bf16_f32 (RNE)
#pragma unroll
      for (int g = 0; g < 2; ++g) {
        pfp[g][0] = (bf16x8){(bf16)s[g][0][0], (bf16)s[g][0][1],
                             (bf16)s[g][0][2], (bf16)s[g][0][3],
                             (bf16)s[g][1][0], (bf16)s[g][1][1],
                             (bf16)s[g][1][2], (bf16)s[g][1][3]};
        pfp[g][1] = (bf16x8){(bf16)s[g][2][0], (bf16)s[g][2][1],
                             (bf16)s[g][2][2], (bf16)s[g][2][3],
                             (bf16)s[g][3][0], (bf16)s[g][3][1],
                             (bf16)s[g][3][2], (bf16)s[g][3][3]};
        // l row-sum via ones A-frag
        ol[g] = mfma_bf(ones, pfp[g][0], ol[g]);
        ol[g] = mfma_bf(ones, pfp[g][1], ol[g]);
      }
    }

    vbPrev = vw;
    vb = (vb == 2) ? 0 : vb + 1;
  }

  // flush PV of the last computed tile (waves that stopped earlier already
  // flushed in-loop; skip condition is monotone in it)
  if ((nk - 1) * 64 <= qw + 31) {
#pragma unroll
    for (int dt = 0; dt < 4; ++dt) {
      bf16x8 vf0 = *(const bf16x8*)(vbPrev + (dt * 16 + mrow) * 32 + quad * 8);
      bf16x8 vf1 =
          *(const bf16x8*)(vbPrev + 2048 + (dt * 16 + mrow) * 32 + quad * 8);
      o[0][dt] = mfma_bf(vf0, pfp[0][0], o[0][dt]);
      o[0][dt] = mfma_bf(vf1, pfp[0][1], o[0][dt]);
      o[1][dt] = mfma_bf(vf0, pfp[1][0], o[1][dt]);
      o[1][dt] = mfma_bf(vf1, pfp[1][1], o[1][dt]);
    }
  }

  __syncthreads();   // all K/V readers done; reuse smem as Osh[4][32][72]
  u16* Osh = smem;

  // epilogue: normalize, transpose O^T -> O through per-wave LDS, store
#pragma unroll
  for (int g = 0; g < 2; ++g) {
    const float inv = 1.f / ol[g][0];
#pragma unroll
    for (int dt = 0; dt < 4; ++dt)
#pragma unroll
      for (int r = 0; r < 4; ++r)
        Osh[(w * 32 + g * 16 + mrow) * 72 + dt * 16 + quad * 4 + r] =
            cvt_bf16(o[g][dt][r] * inv);
  }
#pragma unroll
  for (int p = 0; p < 4; ++p) {
    int ql = (lane >> 3) + 8 * p;
    int ch = lane & 7;
    u16x8 v = *(const u16x8*)&Osh[(w * 32 + ql) * 72 + ch * 8];
    int t = q0 + w * 32 + ql;
    *(u16x8*)(aout + ((size_t)(bb * 2048 + t)) * 1024 + h * 64 + ch * 8) = v;
  }
}

extern "C" void kernel_launch(void* const* d_in, const int* in_sizes, int n_in,
                              void* d_out, int out_size, void* d_ws, size_t ws_size,
                              hipStream_t stream) {
  const float* x  = (const float*)d_in[0];
  const float* Wq = (const float*)d_in[1];
  const float* Wk = (const float*)d_in[2];
  const float* Wv = (const float*)d_in[3];
  const float* Wo = (const float*)d_in[4];

  u16* qkv   = (u16*)d_ws;
  u16* vperm = qkv + (size_t)3 * 64 * 2048 * 64;
  u16* aout  = vperm + (size_t)64 * 64 * 2048;
  u16* xtok  = aout + (size_t)8192 * 1024;
  u16* xpos  = xtok + (size_t)8192 * 512;
  u16* Wt    = xpos + (size_t)8192 * 512;
  u16* WoT   = Wt + (size_t)3 * 1024 * 512;
  float* out = (float*)d_out;

  prep<<<dim3(1024 + 8192), dim3(256), 0, stream>>>(x, Wq, Wk, Wv, Wo, xtok,
                                                    xpos, Wt, WoT);
  gemm_qkv128<<<dim3(8, 64, 3), dim3(256), 0, stream>>>(xtok, xpos, Wt, qkv, vperm);
  attn<<<dim3(64, 16), dim3(256), 0, stream>>>(qkv, vperm, aout);
  gemm_out128<<<dim3(8, 64), dim3(256), 0, stream>>>(aout, WoT, out);
}

// Round 11
// 188.866 us; speedup vs baseline: 1.0051x; 1.0051x over previous
//
#include <hip/hip_runtime.h>
#include <stdint.h>

// SplitAttention: x->(x_tok|x_pos); Q=x_pos@Wq K=x_pos@Wk V=x_tok@Wv;
// causal 16-head attention (d=64); out = attn @ Wo. All MFMA bf16.
//
// R17: revert attn to the R14 structure (best measured 44.6us; R16's
// cross-iteration PV pipelining regressed to 50us -- inter-wave TLP at 16
// waves/CU already overlapped MFMA/VALU, and the restructure cost 8KB LDS,
// +8 VGPR, and extra branches for overlap the CU scheduler provided free).
// GEMMs/prep kept at R15 (128x128 BK=32 triple-buffer, 3 blocks/CU).

typedef unsigned short u16;
typedef __bf16 bf16;
typedef bf16 bf16x8 __attribute__((ext_vector_type(8)));
typedef u16 u16x8 __attribute__((ext_vector_type(8)));
typedef u16 u16x4 __attribute__((ext_vector_type(4)));
typedef float f32x4 __attribute__((ext_vector_type(4)));
typedef uint32_t u32x4 __attribute__((ext_vector_type(4)));

__device__ __forceinline__ u16 cvt_bf16(float f) {
  uint32_t u = __builtin_bit_cast(uint32_t, f);
  u += 0x7FFFu + ((u >> 16) & 1u);   // RNE
  return (u16)(u >> 16);
}

__device__ __forceinline__ f32x4 mfma_bf(bf16x8 a, bf16x8 b, f32x4 c) {
  return __builtin_amdgcn_mfma_f32_16x16x32_bf16(a, b, c, 0, 0, 0);
}

typedef __attribute__((address_space(1))) const uint32_t g_u32;
typedef __attribute__((address_space(3))) uint32_t l_u32;
__device__ __forceinline__ void gload16(const u16* g, u16* l) {
  __builtin_amdgcn_global_load_lds((g_u32*)g, (l_u32*)l, 16, 0, 0);
}

// ---------------- merged prep: gid<1024 -> W[k][n] f32 -> Wt[n][k] bf16
// (z=0..2: 512x1024; z=3: Wo 1024x1024); gid>=1024 -> x -> tok/pos split.
__global__ __launch_bounds__(256) void prep(
    const float* __restrict__ x, const float* __restrict__ Wq,
    const float* __restrict__ Wk, const float* __restrict__ Wv,
    const float* __restrict__ Wo, u16* __restrict__ xtok,
    u16* __restrict__ xpos, u16* __restrict__ Wt, u16* __restrict__ WoT) {
  const int gid = blockIdx.x;
  const int tid = threadIdx.x;
  if (gid < 1024) {
    const int z = gid >> 8;
    const float* src = (z == 0) ? Wq : (z == 1) ? Wk : (z == 2) ? Wv : Wo;
    const int K = (z == 3) ? 1024 : 512;
    u16* dst = (z == 3) ? WoT : (Wt + (size_t)z * 1024 * 512);
    const int k0 = ((gid >> 4) & 15) * 64, n0 = (gid & 15) * 64;
    if (k0 >= K) return;
    __shared__ u16 T[64][68];
    const int r = tid >> 4, c = (tid & 15) * 4;
#pragma unroll
    for (int i = 0; i < 4; i++) {
      float4 v = *(const float4*)(src + (size_t)(k0 + r + i * 16) * 1024 + n0 + c);
      u16x4 b = {cvt_bf16(v.x), cvt_bf16(v.y), cvt_bf16(v.z), cvt_bf16(v.w)};
      *(u16x4*)&T[r + i * 16][c] = b;
    }
    __syncthreads();
#pragma unroll
    for (int i = 0; i < 4; i++) {
      int n = r + i * 16;
      u16x4 v;
#pragma unroll
      for (int j = 0; j < 4; j++) v[j] = T[c + j][n];
      *(u16x4*)(dst + (size_t)(n0 + n) * K + k0 + c) = v;
    }
  } else {
    int idx = (gid - 1024) * 256 + tid;
    int row = idx >> 8;
    int c4 = (idx & 255) * 4;
    float4 v = *(const float4*)(x + (size_t)row * 1024 + c4);
    u16x4 b = {cvt_bf16(v.x), cvt_bf16(v.y), cvt_bf16(v.z), cvt_bf16(v.w)};
    u16* dst = (c4 < 512) ? (xtok + (size_t)row * 512 + c4)
                          : (xpos + (size_t)row * 512 + c4 - 512);
    *(u16x4*)dst = b;
  }
}

// ================= 128x128 BK=32 triple-buffer GEMM core =================
// 256 threads = 4 waves (2M x 2N), per-wave C = 64x64, acc[4][4].
// LDS 48KB -> 3 blocks/CU. One phase per K-tile t: {8 ds_read_b128/wave of
// buf t%3 || stage tile t+2 -> buf (t+2)%3 (4 gload_lds/thread) -> barrier
// -> lgkmcnt(0) -> 16 MFMA -> vmcnt(4) -> barrier}. WAR-safe: staged buf
// != read buf; its last readers drained one barrier earlier.
// Rows are 4x 16B slots; XOR swizzle slot^=(row&3) both-sides.

#define YLD(P) {                                                             \
  const u16* pa_ = rA + (P)*4096;                                            \
  af[0] = *(const bf16x8*)(pa_ + 0*512 + colx);                              \
  af[1] = *(const bf16x8*)(pa_ + 1*512 + colx);                              \
  af[2] = *(const bf16x8*)(pa_ + 2*512 + colx);                              \
  af[3] = *(const bf16x8*)(pa_ + 3*512 + colx);                              \
  const u16* pb_ = rB + (P)*4096;                                            \
  bf[0] = *(const bf16x8*)(pb_ + 0*512 + colx);                              \
  bf[1] = *(const bf16x8*)(pb_ + 1*512 + colx);                              \
  bf[2] = *(const bf16x8*)(pb_ + 2*512 + colx);                              \
  bf[3] = *(const bf16x8*)(pb_ + 3*512 + colx); }

#define YMM {                                                                \
  acc[0][0] = mfma_bf(af[0], bf[0], acc[0][0]);                              \
  acc[0][1] = mfma_bf(af[0], bf[1], acc[0][1]);                              \
  acc[0][2] = mfma_bf(af[0], bf[2], acc[0][2]);                              \
  acc[0][3] = mfma_bf(af[0], bf[3], acc[0][3]);                              \
  acc[1][0] = mfma_bf(af[1], bf[0], acc[1][0]);                              \
  acc[1][1] = mfma_bf(af[1], bf[1], acc[1][1]);                              \
  acc[1][2] = mfma_bf(af[1], bf[2], acc[1][2]);                              \
  acc[1][3] = mfma_bf(af[1], bf[3], acc[1][3]);                              \
  acc[2][0] = mfma_bf(af[2], bf[0], acc[2][0]);                              \
  acc[2][1] = mfma_bf(af[2], bf[1], acc[2][1]);                              \
  acc[2][2] = mfma_bf(af[2], bf[2], acc[2][2]);                              \
  acc[2][3] = mfma_bf(af[2], bf[3], acc[2][3]);                              \
  acc[3][0] = mfma_bf(af[3], bf[0], acc[3][0]);                              \
  acc[3][1] = mfma_bf(af[3], bf[1], acc[3][1]);                              \
  acc[3][2] = mfma_bf(af[3], bf[2], acc[3][2]);                              \
  acc[3][3] = mfma_bf(af[3], bf[3], acc[3][3]); }

#define YST(P, KT) {                                                         \
  gload16(gA + (KT)*32, lA + (P)*4096);                                      \
  gload16(gA + (size_t)64*Kd + (KT)*32, lA + (P)*4096 + 2048);               \
  gload16(gB + (KT)*32, lB + (P)*4096);                                      \
  gload16(gB + (size_t)64*Kd + (KT)*32, lB + (P)*4096 + 2048); }

#define YPH_MID  asm volatile("" ::: "memory"); __builtin_amdgcn_s_barrier();\
  asm volatile("s_waitcnt lgkmcnt(0)" ::: "memory");                         \
  __builtin_amdgcn_s_setprio(1);

#define YPH_END  __builtin_amdgcn_s_setprio(0);                              \
  asm volatile("s_waitcnt vmcnt(4)" ::: "memory");                           \
  asm volatile("" ::: "memory"); __builtin_amdgcn_s_barrier();

template <int Kd>
__device__ __forceinline__ void gemm128_core(
    const u16* __restrict__ Aptr, const u16* __restrict__ Bptr,
    int m0, int n0, u16* smem, f32x4 (&acc)[4][4]) {
  constexpr int NKT = Kd / 32;
  const int tid = threadIdx.x;
  const int lane = tid & 63;
  const int mrow = lane & 15, quad = lane >> 4;
  const int w = tid >> 6, wm = w >> 1, wn = w & 1;

  u16* As = smem;                 // 3 x 4096 u16 (8KB per buf)
  u16* Bs = smem + 12288;         // 3 x 4096 u16

  // staging: thread -> (row = tid>>2 (+64 second load), 16B slot = tid&3)
  const int lrs = tid >> 2, sp4 = tid & 3;
  const int slog = sp4 ^ (lrs & 3);          // pre-swizzled global slot
  const u16* gA = Aptr + (size_t)(m0 + lrs) * Kd + slog * 8;
  const u16* gB = Bptr + (size_t)(n0 + lrs) * Kd + slog * 8;
  u16* lA = As + tid * 8;
  u16* lB = Bs + tid * 8;

  // reads: swizzled slot offset (u16 units), key = (mrow&3)*8
  const int colx = ((quad ^ (mrow & 3)) * 8);
  const u16* rA = As + (wm * 64 + mrow) * 32;
  const u16* rB = Bs + (wn * 64 + mrow) * 32;

  bf16x8 af[4], bf[4];

  // prologue: stage tiles 0 (buf0) and 1 (buf1); gate tile 0 -> vmcnt(4)
  YST(0, 0) YST(1, 1)
  asm volatile("s_waitcnt vmcnt(4)" ::: "memory");
  asm volatile("" ::: "memory");
  __builtin_amdgcn_s_barrier();

  int p = 0, ps = 2;
  for (int t = 0; t < NKT; ++t) {
    const int kt = (t + 2 < NKT) ? t + 2 : NKT - 1;  // clamp keeps vmcnt uniform
    YLD(p)
    YST(ps, kt)
    YPH_MID
    YMM
    YPH_END
    p = (p == 2) ? 0 : p + 1;
    ps = (ps == 2) ? 0 : ps + 1;
  }
  asm volatile("s_waitcnt vmcnt(0)" ::: "memory");  // drain clamped tail stages
  __builtin_amdgcn_s_barrier();
}

// XCD-aware remap (bijective, nwg = 8*64 = 512, 512%8 == 0): each XCD gets
// 64 consecutive work-ids = an 8x8 tile patch (A panel 1MB + B 1MB ~ L2).
__device__ __forceinline__ void xcd_remap(int& bx, int& by) {
  int flat = blockIdx.x + 8 * blockIdx.y;
  int wg = (flat & 7) * 64 + (flat >> 3);
  bx = wg & 7;
  by = wg >> 3;
}

// ---------------- QKV projection, 128x128 BK=32 triple-buffer
__global__ __launch_bounds__(256, 3) void gemm_qkv128(
    const u16* __restrict__ xtok, const u16* __restrict__ xpos,
    const u16* __restrict__ Wt, u16* __restrict__ qkv,
    u16* __restrict__ vperm) {
  const int z = blockIdx.z;
  const u16* A = (z == 2) ? xtok : xpos;
  const u16* Bt = Wt + (size_t)z * 1024 * 512;
  u16* outp = qkv + (size_t)z * (64u * 2048u * 64u);
  const float osc = (z == 0) ? 0.18033688011112042f : 1.0f;  // 0.125*log2e
  int bx, by;
  xcd_remap(bx, by);
  const int m0 = by * 128, n0 = bx * 128;

  __shared__ __align__(16) u16 smem[24576];
  f32x4 acc[4][4];
#pragma unroll
  for (int i = 0; i < 4; i++)
#pragma unroll
    for (int j = 0; j < 4; j++) acc[i][j] = (f32x4){0.f, 0.f, 0.f, 0.f};

  gemm128_core<512>(A, Bt, m0, n0, smem, acc);

  const int tid = threadIdx.x;
  const int lane = tid & 63;
  const int mrow = lane & 15, quad = lane >> 4;
  const int w = tid >> 6, wm = w >> 1, wn = w & 1;

  if (z != 2) {
#pragma unroll
    for (int mi = 0; mi < 4; mi++)
#pragma unroll
      for (int ni = 0; ni < 4; ni++)
#pragma unroll
        for (int r = 0; r < 4; r++) {
          int m = m0 + wm * 64 + mi * 16 + quad * 4 + r;
          int n = n0 + wn * 64 + ni * 16 + mrow;
          int bb = m >> 11, t = m & 2047;
          int h = n >> 6, d = n & 63;
          outp[(((size_t)(bb * 16 + h)) * 2048 + t) * 64 + d] =
              cvt_bf16(acc[mi][ni][r] * osc);
        }
  } else {
#pragma unroll
    for (int mi = 0; mi < 4; mi++)
#pragma unroll
      for (int ni = 0; ni < 4; ni++)
#pragma unroll
        for (int r = 0; r < 4; r++) {
          int m = m0 + wm * 64 + mi * 16 + quad * 4 + r;
          int n = n0 + wn * 64 + ni * 16 + mrow;
          int bb = m >> 11, t = m & 2047;
          int h = n >> 6, d = n & 63;
          int k6 = t & 63;
          int pos = (k6 & 32) + ((k6 >> 4) & 1) * 4 + ((k6 >> 2) & 3) * 8 +
                    (k6 & 3);
          vperm[(((size_t)(bb * 16 + h)) * 64 + d) * 2048 + (t & ~63) + pos] =
              cvt_bf16(acc[mi][ni][r]);
        }
  }
}

// ---------------- Output projection, 128x128 BK=32 triple-buffer -> f32
__global__ __launch_bounds__(256, 3) void gemm_out128(
    const u16* __restrict__ Am, const u16* __restrict__ WoT,
    float* __restrict__ out) {
  int bx, by;
  xcd_remap(bx, by);
  const int m0 = by * 128, n0 = bx * 128;

  __shared__ __align__(16) u16 smem[24576];
  f32x4 acc[4][4];
#pragma unroll
  for (int i = 0; i < 4; i++)
#pragma unroll
    for (int j = 0; j < 4; j++) acc[i][j] = (f32x4){0.f, 0.f, 0.f, 0.f};

  gemm128_core<1024>(Am, WoT, m0, n0, smem, acc);

  const int tid = threadIdx.x;
  const int lane = tid & 63;
  const int mrow = lane & 15, quad = lane >> 4;
  const int w = tid >> 6, wm = w >> 1, wn = w & 1;

#pragma unroll
  for (int mi = 0; mi < 4; mi++)
#pragma unroll
    for (int ni = 0; ni < 4; ni++)
#pragma unroll
      for (int r = 0; r < 4; r++) {
        int m = m0 + wm * 64 + mi * 16 + quad * 4 + r;
        int n = n0 + wn * 64 + ni * 16 + mrow;
        out[(size_t)m * 1024 + n] = acc[mi][ni][r];
      }
}

// ---------------- Flash attention (S^T / O^T, no max, 128-row q-tiles)
// R14 structure (best measured, 44.6us): one 128-row q-tile per block,
// grid (64,16), longest-first (qt = 15-by). 2 q-groups of 16 rows per
// wave. K/V LDS double-buffered, ONE __syncthreads per k-iter; register
// prefetch issued before the barrier. launch_bounds(256,3) -> 72 VGPR,
// no spill. P-frag packing via compiler bf16 casts (v_cvt_pk_bf16_f32).
__global__ __launch_bounds__(256, 3) void attn(
    const u16* __restrict__ qkv, const u16* __restrict__ vperm,
    u16* __restrict__ aout) {
  const int bh = blockIdx.x;
  const int qt = 15 - blockIdx.y;   // 128-row q-tile, longest first
  const int bb = bh >> 4, h = bh & 15;
  const u16* Qp = qkv + (size_t)bh * (2048 * 64);
  const u16* Kp = qkv + (size_t)(64 + bh) * (2048 * 64);
  const u16* Vp = vperm + (size_t)bh * (64 * 2048);

  // [buf][section: K0,K1,V0,V1][64*32]
  __shared__ __align__(16) u16 smem[2][4][64 * 32];

  const int tid = threadIdx.x;
  const int lane = tid & 63;
  const int w = tid >> 6;
  const int mrow = lane & 15;
  const int quad = lane >> 4;
  const int srow = w * 16 + (lane >> 2);
  const int sc = (lane & 3) * 8;
  const int soff = srow * 32 + sc;

  const u16x8 onesu = {0x3F80, 0x3F80, 0x3F80, 0x3F80,
                       0x3F80, 0x3F80, 0x3F80, 0x3F80};
  const bf16x8 ones = __builtin_bit_cast(bf16x8, onesu);

  const u16* kgb = Kp + (size_t)srow * 64 + sc;   // + k0*64 per tile
  const u16* vgb = Vp + (size_t)srow * 2048 + sc; // + k0 per tile

  const int q0 = qt * 128;
  const int nk = 2 * qt + 2;
  const int qw = q0 + w * 32;                  // wave's first q row

  const u16* qbase = Qp + (size_t)(qw + mrow) * 64 + quad * 8;
  const bf16x8 qf00 = *(const bf16x8*)qbase;             // g=0, d 0..31
  const bf16x8 qf01 = *(const bf16x8*)(qbase + 32);      // g=0, d 32..63
  const bf16x8 qf10 = *(const bf16x8*)(qbase + 16 * 64);       // g=1
  const bf16x8 qf11 = *(const bf16x8*)(qbase + 16 * 64 + 32);  // g=1

  f32x4 o[2][4], ol[2];
#pragma unroll
  for (int g = 0; g < 2; ++g) {
#pragma unroll
    for (int dt = 0; dt < 4; ++dt) o[g][dt] = (f32x4){0.f, 0.f, 0.f, 0.f};
    ol[g] = (f32x4){0.f, 0.f, 0.f, 0.f};
  }

  // prefetch tile 0
  u16x8 ka0 = *(const u16x8*)kgb;
  u16x8 ka1 = *(const u16x8*)(kgb + 32);
  u16x8 va0 = *(const u16x8*)vgb;
  u16x8 va1 = *(const u16x8*)(vgb + 32);

  for (int it = 0; it < nk; ++it) {
    u16* buf = &smem[it & 1][0][0];
    *(u16x8*)(buf + 0 * 2048 + soff) = ka0;
    *(u16x8*)(buf + 1 * 2048 + soff) = ka1;
    *(u16x8*)(buf + 2 * 2048 + soff) = va0;
    *(u16x8*)(buf + 3 * 2048 + soff) = va1;

    if (it + 1 < nk) {   // issue next tile's loads; land during compute
      const int kn = (it + 1) * 64;
      ka0 = *(const u16x8*)(kgb + (size_t)kn * 64);
      ka1 = *(const u16x8*)(kgb + (size_t)kn * 64 + 32);
      va0 = *(const u16x8*)(vgb + kn);
      va1 = *(const u16x8*)(vgb + kn + 32);
    }

    __syncthreads();   // buf[it&1] visible; prior readers done at barrier it-1

    const int k0 = it * 64;
    if (k0 > qw + 31) continue;   // tile entirely above causal diagonal

    // S^T = K · Q^T  (C: row = key-in-tile = quad*4+r, col = q = mrow)
    f32x4 s[2][4];
#pragma unroll
    for (int nt = 0; nt < 4; ++nt) {
      bf16x8 kf0 = *(const bf16x8*)(buf + 0 * 2048 + (nt * 16 + mrow) * 32 + quad * 8);
      bf16x8 kf1 = *(const bf16x8*)(buf + 1 * 2048 + (nt * 16 + mrow) * 32 + quad * 8);
      f32x4 z0 = (f32x4){0.f, 0.f, 0.f, 0.f};
      z0 = mfma_bf(kf0, qf00, z0);
      s[0][nt] = mfma_bf(kf1, qf01, z0);
      f32x4 z1 = (f32x4){0.f, 0.f, 0.f, 0.f};
      z1 = mfma_bf(kf0, qf10, z1);
      s[1][nt] = mfma_bf(kf1, qf11, z1);
    }

    if (k0 + 63 > qw) {   // diagonal tile for this wave: causal mask
#pragma unroll
      for (int g = 0; g < 2; ++g)
#pragma unroll
        for (int nt = 0; nt < 4; ++nt)
#pragma unroll
          for (int r = 0; r < 4; ++r)
            if (k0 + nt * 16 + quad * 4 + r > qw + g * 16 + mrow)
              s[g][nt][r] = -1e30f;
    }
    // p = exp2(s), no max subtraction (|s| bounded << 127)
#pragma unroll
    for (int g = 0; g < 2; ++g)
#pragma unroll
      for (int nt = 0; nt < 4; ++nt)
#pragma unroll
        for (int r = 0; r < 4; ++r)
          s[g][nt][r] = __builtin_amdgcn_exp2f(s[g][nt][r]);

    // P^T B-frags: compiler pairs casts into v_cvt_pk_bf16_f32 (RNE)
    bf16x8 pf[2][2];
#pragma unroll
    for (int g = 0; g < 2; ++g) {
      pf[g][0] = (bf16x8){(bf16)s[g][0][0], (bf16)s[g][0][1],
                          (bf16)s[g][0][2], (bf16)s[g][0][3],
                          (bf16)s[g][1][0], (bf16)s[g][1][1],
                          (bf16)s[g][1][2], (bf16)s[g][1][3]};
      pf[g][1] = (bf16x8){(bf16)s[g][2][0], (bf16)s[g][2][1],
                          (bf16)s[g][2][2], (bf16)s[g][2][3],
                          (bf16)s[g][3][0], (bf16)s[g][3][1],
                          (bf16)s[g][3][2], (bf16)s[g][3][3]};
      // l row-sum via ones A-frag
      ol[g] = mfma_bf(ones, pf[g][0], ol[g]);
      ol[g] = mfma_bf(ones, pf[g][1], ol[g]);
    }

    // O^T += V^T · P^T  (each vf read feeds both q-groups)
#pragma unroll
    for (int dt = 0; dt < 4; ++dt) {
      bf16x8 vf0 = *(const bf16x8*)(buf + 2 * 2048 + (dt * 16 + mrow) * 32 + quad * 8);
      bf16x8 vf1 = *(const bf16x8*)(buf + 3 * 2048 + (dt * 16 + mrow) * 32 + quad * 8);
      o[0][dt] = mfma_bf(vf0, pf[0][0], o[0][dt]);
      o[0][dt] = mfma_bf(vf1, pf[0][1], o[0][dt]);
      o[1][dt] = mfma_bf(vf0, pf[1][0], o[1][dt]);
      o[1][dt] = mfma_bf(vf1, pf[1][1], o[1][dt]);
    }
  }

  __syncthreads();   // all K/V readers done; reuse smem as Osh[4][32][72]
  u16* Osh = &smem[0][0][0];

  // epilogue: normalize, transpose O^T -> O through per-wave LDS, store
#pragma unroll
  for (int g = 0; g < 2; ++g) {
    const float inv = 1.f / ol[g][0];
#pragma unroll
    for (int dt = 0; dt < 4; ++dt)
#pragma unroll
      for (int r = 0; r < 4; ++r)
        Osh[(w * 32 + g * 16 + mrow) * 72 + dt * 16 + quad * 4 + r] =
            cvt_bf16(o[g][dt][r] * inv);
  }
#pragma unroll
  for (int p = 0; p < 4; ++p) {
    int ql = (lane >> 3) + 8 * p;
    int ch = lane & 7;
    u16x8 v = *(const u16x8*)&Osh[(w * 32 + ql) * 72 + ch * 8];
    int t = q0 + w * 32 + ql;
    *(u16x8*)(aout + ((size_t)(bb * 2048 + t)) * 1024 + h * 64 + ch * 8) = v;
  }
}

extern "C" void kernel_launch(void* const* d_in, const int* in_sizes, int n_in,
                              void* d_out, int out_size, void* d_ws, size_t ws_size,
                              hipStream_t stream) {
  const float* x  = (const float*)d_in[0];
  const float* Wq = (const float*)d_in[1];
  const float* Wk = (const float*)d_in[2];
  const float* Wv = (const float*)d_in[3];
  const float* Wo = (const float*)d_in[4];

  u16* qkv   = (u16*)d_ws;
  u16* vperm = qkv + (size_t)3 * 64 * 2048 * 64;
  u16* aout  = vperm + (size_t)64 * 64 * 2048;
  u16* xtok  = aout + (size_t)8192 * 1024;
  u16* xpos  = xtok + (size_t)8192 * 512;
  u16* Wt    = xpos + (size_t)8192 * 512;
  u16* WoT   = Wt + (size_t)3 * 1024 * 512;
  float* out = (float*)d_out;

  prep<<<dim3(1024 + 8192), dim3(256), 0, stream>>>(x, Wq, Wk, Wv, Wo, xtok,
                                                    xpos, Wt, WoT);
  gemm_qkv128<<<dim3(8, 64, 3), dim3(256), 0, stream>>>(xtok, xpos, Wt, qkv, vperm);
  attn<<<dim3(64, 16), dim3(256), 0, stream>>>(qkv, vperm, aout);
  gemm_out128<<<dim3(8, 64), dim3(256), 0, stream>>>(aout, WoT, out);
}